// Round 9
// baseline (237.147 us; speedup 1.0000x reference)
//
#include <hip/hip_runtime.h>

// Problem constants: B=16, K=8, C=64, L=2048
#define BB 16
#define KK 8
#define CC 64
#define LL 2048

constexpr int CL = CC * LL;               // 131072 elems per batch
constexpr int NELEM = BB * CL;            // 2,097,152
constexpr int TILE = 4096;                // elems per block -> 16 KB runs/stream
constexpr int NBLOCKS = NELEM / TILE;     // 512 blocks; 32/batch (exact)
constexpr int TPB = 256;
constexpr int EPT = TILE / TPB;           // 16 elems per thread (4 float4 groups)
constexpr int CHUNKS = TILE / 256;        // 16 1KB-DMA chunks per stream

#define SIG_OFF 0.11920292202211755f      // 1 - sigmoid(2) = sigmoid(-2)
#define LOG_EPS -16.11809565095832f       // logf(1e-7)

__device__ __forceinline__ float frcp(float x) { return __builtin_amdgcn_rcpf(x); }

// Async global->LDS DMA, 16 B/lane: one instr stages 1 KB contiguous.
__device__ __forceinline__ void load_to_lds16(const float* g, float* l) {
    __builtin_amdgcn_global_load_lds(
        (const __attribute__((address_space(1))) void*)g,
        (__attribute__((address_space(3))) void*)l,
        16, 0, 0);
}

__global__ void init_sldj_kernel(const float* __restrict__ sldj_in,
                                 float* __restrict__ sldj_out) {
    int i = threadIdx.x;
    if (i < BB) sldj_out[i] = sldj_in[i];
}

// 144 KB LDS -> 1 block/CU. Per CU at any instant: ONE 48 KB burst (3 streams
// x 16 KB contiguous) in flight = 768 lines, saturating the per-CU outstanding
// budget with maximal DRAM row locality (the R6->R7 trend: 1KB runs=120us,
// 8KB runs=86us; this tests 16KB runs / 3 streams).
__global__ __launch_bounds__(256) void coupling_kernel(
    const float* __restrict__ x,
    const float* __restrict__ a,
    const float* __restrict__ bv,
    const float* __restrict__ pi,
    const float* __restrict__ mu,
    const float* __restrict__ s,
    float* __restrict__ out,
    float* __restrict__ sldj_out) {

    __shared__ float xab[3 * TILE];        // 48 KB: x | a | b
    __shared__ float kbuf[2][3 * TILE];    // 2 x 48 KB: pi | mu | s for one k
    __shared__ float wsum[4];

    const int blk  = blockIdx.x;
    const int b    = blk >> 5;             // 32 blocks per batch
    const int base = blk * TILE;
    const int kb0  = (b << 20) + (base & (CL - 1));   // b*K*CL + rem

    const int tid  = threadIdx.x;
    const int lane = tid & 63;
    const int wv   = tid >> 6;
    const int l4   = lane * 4;

    // ---- Prologue: stage x,a,b (48 instrs) + k=0 (48 instrs), 12+12/wave ----
#pragma unroll
    for (int j = 0; j < 12; ++j) {
        const int i  = wv * 12 + j;        // 0..47
        const int st = i >> 4;             // stream 0..2
        const int ch = i & 15;             // chunk 0..15
        const float* gp = (st == 0 ? x : st == 1 ? a : bv) + base + ch * 256 + l4;
        load_to_lds16(gp, &xab[st * TILE + ch * 256 + l4]);
    }
#pragma unroll
    for (int j = 0; j < 12; ++j) {
        const int i  = wv * 12 + j;
        const int st = i >> 4;
        const int ch = i & 15;
        const float* gp = (st == 0 ? pi : st == 1 ? mu : s) + kb0 + ch * 256 + l4;
        load_to_lds16(gp, &kbuf[0][st * TILE + ch * 256 + l4]);
    }
    __syncthreads();   // own-wave vmcnt(0) + barrier: everything staged

    // Cache x in registers: 4 groups of float4 at g*1024 + 4*tid
    float xs[EPT];
#pragma unroll
    for (int g = 0; g < 4; ++g) {
        const float4 v = *(const float4*)&xab[g * 1024 + 4 * tid];
        xs[g * 4 + 0] = v.x; xs[g * 4 + 1] = v.y;
        xs[g * 4 + 2] = v.z; xs[g * 4 + 3] = v.w;
    }

    float Spi[EPT], Nc[EPT], N1[EPT], Np[EPT];
#pragma unroll
    for (int e = 0; e < EPT; ++e) { Spi[e] = Nc[e] = N1[e] = Np[e] = 0.f; }

    for (int k = 0; k < KK; ++k) {
        const int cur = k & 1;
        if (k + 1 < KK) {                  // issue k+1 burst before computing k
#pragma unroll
            for (int j = 0; j < 12; ++j) {
                const int i  = wv * 12 + j;
                const int st = i >> 4;
                const int ch = i & 15;
                const float* gp = (st == 0 ? pi : st == 1 ? mu : s)
                                  + kb0 + (k + 1) * CL + ch * 256 + l4;
                load_to_lds16(gp, &kbuf[1 - cur][st * TILE + ch * 256 + l4]);
            }
        }
#pragma unroll
        for (int g = 0; g < 4; ++g) {
            const float4 p4 = *(const float4*)&kbuf[cur][0 * TILE + g * 1024 + 4 * tid];
            const float4 m4 = *(const float4*)&kbuf[cur][1 * TILE + g * 1024 + 4 * tid];
            const float4 s4 = *(const float4*)&kbuf[cur][2 * TILE + g * 1024 + 4 * tid];
            const float ps[4] = {p4.x, p4.y, p4.z, p4.w};
            const float ms[4] = {m4.x, m4.y, m4.z, m4.w};
            const float ss[4] = {s4.x, s4.y, s4.z, s4.w};
#pragma unroll
            for (int e = 0; e < 4; ++e) {
                const int ei = g * 4 + e;
                const float invstd = __expf(-ss[e]);
                const float z      = (xs[ei] - ms[e]) * invstd;
                const float tt = __expf(-fabsf(z));
                const float r  = frcp(1.f + tt);
                const float tr = tt * r;
                const float sig  = (z >= 0.f) ? r  : tr;
                const float osig = (z >= 0.f) ? tr : r;
                const float ek = __expf(ps[e]);
                Spi[ei] += ek;
                Nc [ei] += ek * sig;
                N1 [ei] += ek * osig;
                Np [ei] += ek * invstd * sig * osig;
            }
        }
        __syncthreads();   // drain k+1 DMA (own wave) + guard kbuf reuse
    }

    // ---- Epilogue ----
    float contrib = 0.f;
#pragma unroll
    for (int g = 0; g < 4; ++g) {
        const float4 a4 = *(const float4*)&xab[1 * TILE + g * 1024 + 4 * tid];
        const float4 b4 = *(const float4*)&xab[2 * TILE + g * 1024 + 4 * tid];
        const float as[4] = {a4.x, a4.y, a4.z, a4.w};
        const float bs[4] = {b4.x, b4.y, b4.z, b4.w};
        float4 o4;
        float* op = (float*)&o4;
#pragma unroll
        for (int e = 0; e < 4; ++e) {
            const int ei = g * 4 + e;
            const float lSpi = __logf(Spi[ei]);
            const float lu   = fmaxf(__logf(Nc[ei]) - lSpi, LOG_EPS);
            const float lomu = fmaxf(__logf(N1[ei]) - lSpi, LOG_EPS);
            const float y        = lu - lomu;     // logit(u)
            const float ldj_term = -lu - lomu;
            const float log_pdf  = __logf(Np[ei]) - lSpi;

            const float av = as[e] + 2.f;
            const float t2 = __expf(-fabsf(av));
            const float r2 = frcp(1.f + t2);
            const float sc = ((av >= 0.f) ? r2 : t2 * r2) + SIG_OFF;

            op[e] = (y + bs[e]) * sc;
            contrib += log_pdf + ldj_term + __logf(sc);
        }
        *(float4*)(out + base + g * 1024 + 4 * tid) = o4;
    }

    // block reduction, one atomicAdd per block (block within batch b)
#pragma unroll
    for (int off = 32; off > 0; off >>= 1)
        contrib += __shfl_down(contrib, off, 64);
    if (lane == 0) wsum[wv] = contrib;
    __syncthreads();
    if (tid == 0) {
        atomicAdd(&sldj_out[b], wsum[0] + wsum[1] + wsum[2] + wsum[3]);
    }
}

extern "C" void kernel_launch(void* const* d_in, const int* in_sizes, int n_in,
                              void* d_out, int out_size, void* d_ws, size_t ws_size,
                              hipStream_t stream) {
    const float* x    = (const float*)d_in[0];
    const float* a    = (const float*)d_in[1];
    const float* bv   = (const float*)d_in[2];
    const float* pi   = (const float*)d_in[3];
    const float* mu   = (const float*)d_in[4];
    const float* s    = (const float*)d_in[5];
    const float* sldj = (const float*)d_in[6];

    float* out      = (float*)d_out;
    float* sldj_out = out + (size_t)NELEM;  // outputs concat: out, then sldj

    init_sldj_kernel<<<1, 64, 0, stream>>>(sldj, sldj_out);
    coupling_kernel<<<NBLOCKS, TPB, 0, stream>>>(x, a, bv, pi, mu, s, out, sldj_out);
}